// Round 8
// baseline (289.673 us; speedup 1.0000x reference)
//
#include <hip/hip_runtime.h>
#include <hip/hip_bf16.h>

typedef __bf16 bf16_t;
typedef bf16_t bf16x8 __attribute__((ext_vector_type(8)));
typedef bf16_t bf16x4 __attribute__((ext_vector_type(4)));
typedef float  f32x4  __attribute__((ext_vector_type(4)));

#define BM 256
#define BN 128
#define BK 32            // one K-tile
#define ABUF (BM * BK)   // bf16 tile: 8192 elems
#define BBUF (BN * BK)   // 4096 elems

enum { EPI_NONE = 0, EPI_THRESH = 1, EPI_BIAS = 2 };

__device__ __forceinline__ void memfence() { asm volatile("" ::: "memory"); }
__device__ __forceinline__ void blockbar() {
    memfence(); __builtin_amdgcn_s_barrier(); memfence();
}

#define GLD16(src, dst) __builtin_amdgcn_global_load_lds( \
    (const __attribute__((address_space(1))) void*)(src), \
    (__attribute__((address_space(3))) void*)(dst), 16, 0, 0)

// ============================================================================
// bf16 x bf16 tile (verbatim from round 6, measured): 256x128, BK=32, 8 waves
// (4M x 2N) of 64x64, 3-deep LDS (72 KiB), steady vmcnt(3), one barrier/tile,
// 2 blocks/CU. Used by the Wc sub-GEMM and gemm_out.
// ============================================================================
template <int EPI, typename CT>
__device__ __forceinline__
void gemm_tile(const bf16_t* __restrict__ A, const bf16_t* __restrict__ B,
               CT* __restrict__ C, const float* __restrict__ bias,
               int m0, int n0, int N, int K,
               bf16_t* __restrict__ As, bf16_t* __restrict__ Bs)
{
    const int lane = threadIdx.x & 63;
    const int wave = threadIdx.x >> 6;
    const int wm = wave >> 1;
    const int wn = wave & 1;

    const int fm   = lane & 15;
    const int q    = lane >> 4;
    const int fsw2 = (fm ^ (fm >> 2)) & 3;

    const int NT = K / BK;               // 24

    const bf16_t* ga0; const bf16_t* ga1; const bf16_t* gb;
    {
        const int u0 = (wave * 2) * 64 + lane;
        const int r0 = u0 >> 2;
        ga0 = A + (size_t)(m0 + r0) * K + (((u0 & 3) ^ ((r0 ^ (r0 >> 2)) & 3)) * 8);
        const int u1 = (wave * 2 + 1) * 64 + lane;
        const int r1 = u1 >> 2;
        ga1 = A + (size_t)(m0 + r1) * K + (((u1 & 3) ^ ((r1 ^ (r1 >> 2)) & 3)) * 8);
        const int ub = wave * 64 + lane;
        const int rb = ub >> 2;
        gb  = B + (size_t)(n0 + rb) * K + (((ub & 3) ^ ((rb ^ (rb >> 2)) & 3)) * 8);
    }
    const int la0 = wave * 1024;
    const int la1 = wave * 1024 + 512;
    const int lb  = wave * 512;

#define STAGE(tt, Ad, Bd) do {                                   \
    GLD16(ga0 + (size_t)(tt) * BK, (Ad) + la0);                  \
    GLD16(ga1 + (size_t)(tt) * BK, (Ad) + la1);                  \
    GLD16(gb  + (size_t)(tt) * BK, (Bd) + lb);                   \
} while (0)

    f32x4 acc[4][4];
#pragma unroll
    for (int i = 0; i < 4; ++i)
#pragma unroll
        for (int j = 0; j < 4; ++j) acc[i][j] = (f32x4){0.f, 0.f, 0.f, 0.f};

    STAGE(0, As, Bs);
    STAGE(1, As + ABUF, Bs + BBUF);
    asm volatile("s_waitcnt vmcnt(3)" ::: "memory");
    blockbar();

    int bc = 0;
    for (int t = 0; t < NT; ++t) {
        const bf16_t* __restrict__ Ab = As + bc * ABUF;
        const bf16_t* __restrict__ Bb = Bs + bc * BBUF;
        const int bs2 = (bc >= 1) ? bc - 1 : 2;
        const bool do_stage = (t + 2 < NT);

        bf16x8 af[4], bfr[4];
#pragma unroll
        for (int i = 0; i < 4; ++i) {
            const int row = wm * 64 + i * 16 + fm;
            af[i] = *(const bf16x8*)(Ab + (size_t)(row * 4 + (q ^ fsw2)) * 8);
        }
#pragma unroll
        for (int j = 0; j < 4; ++j) {
            const int row = wn * 64 + j * 16 + fm;
            bfr[j] = *(const bf16x8*)(Bb + (size_t)(row * 4 + (q ^ fsw2)) * 8);
        }
        if (do_stage) STAGE(t + 2, As + bs2 * ABUF, Bs + bs2 * BBUF);

        __builtin_amdgcn_s_setprio(1);
#pragma unroll
        for (int i = 0; i < 4; ++i)
#pragma unroll
            for (int j = 0; j < 4; ++j)
                acc[i][j] = __builtin_amdgcn_mfma_f32_16x16x32_bf16(
                    af[i], bfr[j], acc[i][j], 0, 0, 0);
        __builtin_amdgcn_s_setprio(0);

        if (t < NT - 1) {
            asm volatile("s_waitcnt lgkmcnt(0)" ::: "memory");
            if (do_stage) asm volatile("s_waitcnt vmcnt(3)" ::: "memory");
            else          asm volatile("s_waitcnt vmcnt(0)" ::: "memory");
            blockbar();
        }
        bc = (bc >= 2) ? 0 : bc + 1;
    }

#pragma unroll
    for (int i = 0; i < 4; ++i) {
#pragma unroll
        for (int j = 0; j < 4; ++j) {
            const int col = n0 + wn * 64 + j * 16 + fm;
            float bv = 0.f;
            if (EPI == EPI_BIAS) bv = bias[col];
#pragma unroll
            for (int r = 0; r < 4; ++r) {
                const int row = m0 + wm * 64 + i * 16 + q * 4 + r;
                float v = acc[i][j][r];
                if (EPI == EPI_THRESH) v = (fabsf(v) > 1e-3f) ? v : 0.f;
                if (EPI == EPI_BIAS) v += bv;
                C[(size_t)row * N + col] = (CT)v;
            }
        }
    }
#undef STAGE
}

// ============================================================================
// A-fp32 tile: h = thresh(x_f32 @ Ub^T). x is staged RAW fp32 via
// global_load_lds (async, no VALU on staging path -- the R4 failure was
// reg-staging, not fusion per se) and converted fp32->bf16 at fragment-read
// time (2x ds_read_b128 + 8 casts per A-frag; compiler emits cvt_pk).
// LDS: A 2 x 32 KiB fp32 + B 2 x 8 KiB bf16 = 80 KiB -> 2 blocks/CU.
// 2-deep: stage t+1 at tile-t top into buf^1 (freed at the t-1 boundary);
// boundary = lgkm(0) + vmcnt(0) + barrier (drain covered by the co-resident
// block -- R3 showed 2-deep drain is not binding; R6 showed occupancy is).
// A swizzle: 8 chunks of 16B (4 f32) per 128B row, chunk ^= row&7 (the
// R2-proven 3-bit geometry, 0 measured conflicts). B as in round 6.
// ============================================================================
template <int EPI>
__device__ __forceinline__
void gemm_h_af32(const float* __restrict__ A, const bf16_t* __restrict__ B,
                 bf16_t* __restrict__ C, int m0, int n0, int N, int K,
                 float* __restrict__ As, bf16_t* __restrict__ Bs)
{
    const int lane = threadIdx.x & 63;
    const int wave = threadIdx.x >> 6;
    const int wm = wave >> 1;
    const int wn = wave & 1;

    const int fm   = lane & 15;
    const int q    = lane >> 4;
    const int fsw  = fm & 7;
    const int fsw2 = (fm ^ (fm >> 2)) & 3;

    const int NT = K / BK;               // 24

    // A: 2048 units (256 rows x 8 chunks of 4 f32); 4 gld slots per wave.
    const float* gA0; const float* gA1; const float* gA2; const float* gA3;
    {
        const int u0 = (wave * 4 + 0) * 64 + lane; const int r0 = u0 >> 3;
        gA0 = A + (size_t)(m0 + r0) * K + ((u0 & 7) ^ (r0 & 7)) * 4;
        const int u1 = (wave * 4 + 1) * 64 + lane; const int r1 = u1 >> 3;
        gA1 = A + (size_t)(m0 + r1) * K + ((u1 & 7) ^ (r1 & 7)) * 4;
        const int u2 = (wave * 4 + 2) * 64 + lane; const int r2 = u2 >> 3;
        gA2 = A + (size_t)(m0 + r2) * K + ((u2 & 7) ^ (r2 & 7)) * 4;
        const int u3 = (wave * 4 + 3) * 64 + lane; const int r3 = u3 >> 3;
        gA3 = A + (size_t)(m0 + r3) * K + ((u3 & 7) ^ (r3 & 7)) * 4;
    }
    // B: 512 units (128 rows x 4 chunks of 8 bf16); 1 gld slot per wave.
    const bf16_t* gb;
    {
        const int ub = wave * 64 + lane;
        const int rb = ub >> 2;
        gb = B + (size_t)(n0 + rb) * K + (((ub & 3) ^ ((rb ^ (rb >> 2)) & 3)) * 8);
    }
    const int lA = wave * 1024;          // f32 elems: (wave*4)*64*4
    const int lb = wave * 512;           // bf16 elems

#define HSTAGE(tt, Ad, Bd) do {                                  \
    GLD16(gA0 + (size_t)(tt) * BK, (Ad) + lA);                   \
    GLD16(gA1 + (size_t)(tt) * BK, (Ad) + lA + 256);             \
    GLD16(gA2 + (size_t)(tt) * BK, (Ad) + lA + 512);             \
    GLD16(gA3 + (size_t)(tt) * BK, (Ad) + lA + 768);             \
    GLD16(gb  + (size_t)(tt) * BK, (Bd) + lb);                   \
} while (0)

    f32x4 acc[4][4];
#pragma unroll
    for (int i = 0; i < 4; ++i)
#pragma unroll
        for (int j = 0; j < 4; ++j) acc[i][j] = (f32x4){0.f, 0.f, 0.f, 0.f};

    HSTAGE(0, As, Bs);
    asm volatile("s_waitcnt vmcnt(0)" ::: "memory");
    blockbar();

    for (int t = 0; t < NT; ++t) {
        const float*  __restrict__ Ab = As + (t & 1) * (BM * BK);
        const bf16_t* __restrict__ Bb = Bs + (t & 1) * BBUF;

        // issue next-tile staging FIRST (whole tile to cover HBM latency)
        if (t + 1 < NT)
            HSTAGE(t + 1, As + ((t + 1) & 1) * (BM * BK),
                          Bs + ((t + 1) & 1) * BBUF);

        bf16x8 af[4], bfr[4];
#pragma unroll
        for (int i = 0; i < 4; ++i) {
            const int row = wm * 64 + i * 16 + fm;
            const f32x4 lo = *(const f32x4*)(Ab + (size_t)(row * 8 + ((2 * q)     ^ fsw)) * 4);
            const f32x4 hi = *(const f32x4*)(Ab + (size_t)(row * 8 + ((2 * q + 1) ^ fsw)) * 4);
            bf16x8 v;
            v[0] = (bf16_t)lo[0]; v[1] = (bf16_t)lo[1];
            v[2] = (bf16_t)lo[2]; v[3] = (bf16_t)lo[3];
            v[4] = (bf16_t)hi[0]; v[5] = (bf16_t)hi[1];
            v[6] = (bf16_t)hi[2]; v[7] = (bf16_t)hi[3];
            af[i] = v;
        }
#pragma unroll
        for (int j = 0; j < 4; ++j) {
            const int row = wn * 64 + j * 16 + fm;
            bfr[j] = *(const bf16x8*)(Bb + (size_t)(row * 4 + (q ^ fsw2)) * 8);
        }

        __builtin_amdgcn_s_setprio(1);
#pragma unroll
        for (int i = 0; i < 4; ++i)
#pragma unroll
            for (int j = 0; j < 4; ++j)
                acc[i][j] = __builtin_amdgcn_mfma_f32_16x16x32_bf16(
                    af[i], bfr[j], acc[i][j], 0, 0, 0);
        __builtin_amdgcn_s_setprio(0);

        if (t < NT - 1) {
            asm volatile("s_waitcnt lgkmcnt(0)" ::: "memory");
            asm volatile("s_waitcnt vmcnt(0)" ::: "memory");   // t+1 landed
            blockbar();
        }
    }

#pragma unroll
    for (int i = 0; i < 4; ++i) {
#pragma unroll
        for (int j = 0; j < 4; ++j) {
            const int col = n0 + wn * 64 + j * 16 + fm;
#pragma unroll
            for (int r = 0; r < 4; ++r) {
                const int row = m0 + wm * 64 + i * 16 + q * 4 + r;
                float v = acc[i][j][r];
                if (EPI == EPI_THRESH) v = (fabsf(v) > 1e-3f) ? v : 0.f;
                C[(size_t)row * N + col] = (bf16_t)v;
            }
        }
    }
#undef HSTAGE
}

// dispatch 2: blocks 0..17 = Wc = VTb @ Wt^T (bf16 path); blocks 18..785 =
// h = thresh(x_f32 @ Ub^T) (A-fp32 path), bijective XCD swizzle over 768.
// Shared LDS arena: 80 KiB -> exactly 2 blocks/CU.
__global__ __launch_bounds__(512, 4)
void gemm_h_wc(const float* __restrict__ x, const bf16_t* __restrict__ Ub,
               bf16_t* __restrict__ h,
               const bf16_t* __restrict__ VTb, const bf16_t* __restrict__ Wt,
               bf16_t* __restrict__ Wc)
{
    __shared__ __align__(16) char lds[81920];
    const int b = blockIdx.x;
    if (b < 18) {
        bf16_t* As = (bf16_t*)lds;                 // 3*ABUF*2 = 48 KiB
        bf16_t* Bs = (bf16_t*)(lds + 49152);       // 3*BBUF*2 = 24 KiB
        gemm_tile<EPI_NONE, bf16_t>(VTb, Wt, Wc, nullptr,
                                    (b / 6) * BM, (b % 6) * BN, 768, 768, As, Bs);
    } else {
        float*  As = (float*)lds;                  // 2*BM*BK*4 = 64 KiB
        bf16_t* Bs = (bf16_t*)(lds + 65536);       // 2*BBUF*2  = 16 KiB
        const int bb = b - 18;
        const int L = (bb & 7) * 96 + (bb >> 3);
        gemm_h_af32<EPI_THRESH>(x, Ub, h,
                                (L / 6) * BM, (L % 6) * BN, 768, 768, As, Bs);
    }
}

// dispatch 3: out = h @ Wc^T + bias (fp32 store) -- round-6 kernel verbatim
__global__ __launch_bounds__(512, 4)
void gemm_out(const bf16_t* __restrict__ h, const bf16_t* __restrict__ Wc,
              float* __restrict__ out, const float* __restrict__ bias)
{
    __shared__ __align__(16) bf16_t As[3 * ABUF];
    __shared__ __align__(16) bf16_t Bs[3 * BBUF];
    const int b = blockIdx.x;
    const int L = (b & 7) * 96 + (b >> 3);
    gemm_tile<EPI_BIAS, float>(h, Wc, out, bias,
                               (L / 6) * BM, (L % 6) * BN, 768, 768, As, Bs);
}

// dispatch 1: matrices only (x no longer converted!).
// blocks [0,288): U cvt; [288,576): VT cvt; [576,1152): w^T (32x32 tiles)
__global__ __launch_bounds__(256)
void prep(const float* __restrict__ U, const float* __restrict__ VT,
          const float* __restrict__ w,
          bf16_t* __restrict__ Ub, bf16_t* __restrict__ VTb,
          bf16_t* __restrict__ Wt)
{
    __shared__ float tt[32][33];
    const int b = blockIdx.x;
    if (b < 576) {
        const float* src; bf16_t* dst; size_t e;
        if (b < 288) { src = U;  dst = Ub;  e = (size_t)b * 2048; }
        else         { src = VT; dst = VTb; e = (size_t)(b - 288) * 2048; }
        const size_t i = e + (size_t)threadIdx.x * 8;
        const f32x4 v0 = *(const f32x4*)(src + i);
        const f32x4 v1 = *(const f32x4*)(src + i + 4);
        bf16x8 o;
        o[0] = (bf16_t)v0[0]; o[1] = (bf16_t)v0[1];
        o[2] = (bf16_t)v0[2]; o[3] = (bf16_t)v0[3];
        o[4] = (bf16_t)v1[0]; o[5] = (bf16_t)v1[1];
        o[6] = (bf16_t)v1[2]; o[7] = (bf16_t)v1[3];
        *(bf16x8*)(dst + i) = o;
    } else {
        const int t = b - 576;                // 0..575
        const int bx = (t % 24) * 32, by = (t / 24) * 32;
        const int tx = threadIdx.x & 31, ty = threadIdx.x >> 5;  // 32 x 8
#pragma unroll
        for (int i = 0; i < 32; i += 8)
            tt[ty + i][tx] = w[(size_t)(by + ty + i) * 768 + bx + tx];
        __syncthreads();
#pragma unroll
        for (int i = 0; i < 32; i += 8)
            Wt[(size_t)(bx + ty + i) * 768 + by + tx] = (bf16_t)tt[tx][ty + i];
    }
}

extern "C" void kernel_launch(void* const* d_in, const int* in_sizes, int n_in,
                              void* d_out, int out_size, void* d_ws, size_t ws_size,
                              hipStream_t stream)
{
    const float* x    = (const float*)d_in[0];   // (8,4096,768) fp32
    const float* w    = (const float*)d_in[1];   // (768,768) fp32
    const float* bias = (const float*)d_in[2];   // (768,) fp32
    const float* U    = (const float*)d_in[3];   // (768,768) fp32
    const float* VT   = (const float*)d_in[4];   // (768,768) fp32
    float* out = (float*)d_out;                  // (8,4096,768) fp32

    const int D = 768;
    const int M = 8 * 4096;                      // 32768
    const size_t MD = (size_t)M * D;
    const size_t DD = (size_t)D * D;

    char* ws = (char*)d_ws;
    bf16_t* h   = (bf16_t*)ws;                         // MD bf16
    bf16_t* Ub  = (bf16_t*)(ws + MD * 2);              // DD
    bf16_t* VTb = (bf16_t*)(ws + MD * 2 + DD * 2);     // DD
    bf16_t* Wt  = (bf16_t*)(ws + MD * 2 + DD * 4);     // DD: weight^T
    bf16_t* Wc  = (bf16_t*)(ws + MD * 2 + DD * 6);     // DD: VT@weight

    // 1) matrix conversions + transpose (x is consumed fp32 directly)
    prep<<<1152, 256, 0, stream>>>(U, VT, w, Ub, VTb, Wt);
    // 2) Wc = (VT @ weight) [18 blocks] + h = thresh(x @ U^T) [768 blocks]
    gemm_h_wc<<<18 + 768, 512, 0, stream>>>(x, Ub, h, VTb, Wt, Wc);
    // 3) out = h @ Wc^T + bias  (== ((h @ W^T) @ VT^T) + bias)
    gemm_out<<<768, 512, 0, stream>>>(h, Wc, out, bias);
}